// Round 5
// baseline (253.686 us; speedup 1.0000x reference)
//
#include <hip/hip_runtime.h>
#include <hip/hip_bf16.h>

#define B_ 4
#define S_ 2048
#define D_ 1024
#define H_ 16
#define HD_ 64
#define M_TOK 8192   // B*S
#define QSCALE 0.18033688f   // 0.125 * log2(e)

typedef __attribute__((ext_vector_type(4))) float f32x4;
typedef __attribute__((ext_vector_type(8))) short short8;
typedef __attribute__((ext_vector_type(4))) short short4_t;

__device__ inline short f2bf(float f) {
  unsigned u = __builtin_bit_cast(unsigned, f);
  u += 0x7fff + ((u >> 16) & 1);   // RNE
  return (short)(u >> 16);
}
__device__ inline float bf2f(short s) {
  unsigned u = ((unsigned)(unsigned short)s) << 16;
  return __builtin_bit_cast(float, u);
}

typedef __attribute__((address_space(1))) const unsigned int gas_u32;
typedef __attribute__((address_space(3))) unsigned int las_u32;
__device__ inline void gload_lds16(const void* g, void* l) {
  __builtin_amdgcn_global_load_lds((gas_u32*)g, (las_u32*)l, 16, 0, 0);
}

// ---------------- conversion kernels ----------------
__global__ __launch_bounds__(256) void conv_x_kernel(
    const float* __restrict__ x, short* __restrict__ xb) {
  size_t base = ((size_t)blockIdx.x * 256 + threadIdx.x) * 8;
  f32x4 v0 = *reinterpret_cast<const f32x4*>(&x[base]);
  f32x4 v1 = *reinterpret_cast<const f32x4*>(&x[base + 4]);
  short8 o;
  o[0]=f2bf(v0[0]); o[1]=f2bf(v0[1]); o[2]=f2bf(v0[2]); o[3]=f2bf(v0[3]);
  o[4]=f2bf(v1[0]); o[5]=f2bf(v1[1]); o[6]=f2bf(v1[2]); o[7]=f2bf(v1[3]);
  *reinterpret_cast<short8*>(&xb[base]) = o;
}

__global__ __launch_bounds__(256) void conv_wqkv_kernel(
    const float* __restrict__ Wqkv, short* __restrict__ wqkvt) {
  const int h = blockIdx.x;
  const int k0 = blockIdx.y * 32;
  const int tid = threadIdx.x;
  __shared__ short T[192 * 40];
#pragma unroll
  for (int i = 0; i < 6; ++i) {
    int iv = tid + i * 256;
    int k = iv / 48;
    int e4 = (iv % 48) * 4;
    f32x4 v = *reinterpret_cast<const f32x4*>(&Wqkv[((size_t)h * D_ + k0 + k) * 192 + e4]);
#pragma unroll
    for (int j = 0; j < 4; ++j) T[(e4 + j) * 40 + k] = f2bf(v[j]);
  }
  __syncthreads();
#pragma unroll
  for (int i = 0; i < 6; ++i) {
    int iv = tid + i * 256;
    int e = iv >> 3;
    int g4 = iv & 7;
    short4_t o = *reinterpret_cast<const short4_t*>(&T[e * 40 + g4 * 4]);
    *reinterpret_cast<short4_t*>(&wqkvt[(size_t)(h * 192 + e) * 1024 + k0 + g4 * 4]) = o;
  }
}

__global__ __launch_bounds__(256) void conv_wo_kernel(
    const float* __restrict__ Wo, short* __restrict__ wot) {
  const int k0 = blockIdx.x * 32;
  const int n0 = blockIdx.y * 128;
  const int tid = threadIdx.x;
  __shared__ short T[128 * 40];
#pragma unroll
  for (int i = 0; i < 4; ++i) {
    int iv = tid + i * 256;
    int k = iv >> 5;
    int n4 = (iv & 31) * 4;
    f32x4 v = *reinterpret_cast<const f32x4*>(&Wo[(size_t)(k0 + k) * 1024 + n0 + n4]);
#pragma unroll
    for (int j = 0; j < 4; ++j) T[(n4 + j) * 40 + k] = f2bf(v[j]);
  }
  __syncthreads();
#pragma unroll
  for (int i = 0; i < 4; ++i) {
    int iv = tid + i * 256;
    int e = iv >> 3;
    int g4 = iv & 7;
    short4_t o = *reinterpret_cast<const short4_t*>(&T[e * 40 + g4 * 4]);
    *reinterpret_cast<short4_t*>(&wot[(size_t)(n0 + e) * 1024 + k0 + g4 * 4]) = o;
  }
}

// ---------------- m97-style GEMM: C[M][N] = A[M][K] @ Bt[N][K]^T + bias ----------------
template<int EPI>
__global__ __launch_bounds__(256) void gemm_kernel(
    const short* __restrict__ A, const short* __restrict__ Bt,
    const float* __restrict__ bias,
    short* __restrict__ qb, short* __restrict__ kb, short* __restrict__ vt,
    float* __restrict__ out) {
  const int m0 = blockIdx.x * 128;
  const int n0 = blockIdx.y * 128;
  const int tid = threadIdx.x;
  const int lane = tid & 63, wv = tid >> 6;
  const int wr = wv >> 1, wc = wv & 1;
  const int g = lane >> 4, c = lane & 15;

  __shared__ short As[128 * 32];
  __shared__ short Bs[128 * 32];

  const f32x4 zero4 = {0.f, 0.f, 0.f, 0.f};
  f32x4 acc[4][4];
#pragma unroll
  for (int i = 0; i < 4; ++i)
#pragma unroll
    for (int j = 0; j < 4; ++j) acc[i][j] = zero4;

  const int row_l = tid >> 2;
  const int chunk = tid & 3;
  const short* ga = A  + (size_t)(m0 + row_l) * D_ + chunk * 8;
  const short* gb = Bt + (size_t)(n0 + row_l) * D_ + chunk * 8;
  char* lA = (char*)As + tid * 16;
  char* lB = (char*)Bs + tid * 16;

  for (int k0 = 0; k0 < D_; k0 += 32) {
    gload_lds16(ga + k0,            lA);
    gload_lds16(ga + 64 * D_ + k0,  lA + 4096);
    gload_lds16(gb + k0,            lB);
    gload_lds16(gb + 64 * D_ + k0,  lB + 4096);
    asm volatile("s_waitcnt vmcnt(0)" ::: "memory");
    __syncthreads();
    short8 a[4], b[4];
#pragma unroll
    for (int t = 0; t < 4; ++t) {
      a[t] = *reinterpret_cast<const short8*>(&As[(wr * 64 + t * 16 + c) * 32 + g * 8]);
      b[t] = *reinterpret_cast<const short8*>(&Bs[(wc * 64 + t * 16 + c) * 32 + g * 8]);
    }
#pragma unroll
    for (int mt = 0; mt < 4; ++mt)
#pragma unroll
      for (int nt = 0; nt < 4; ++nt)
        acc[mt][nt] = __builtin_amdgcn_mfma_f32_16x16x32_bf16(a[mt], b[nt], acc[mt][nt], 0, 0, 0);
    __syncthreads();
  }

#pragma unroll
  for (int mt = 0; mt < 4; ++mt) {
#pragma unroll
    for (int nt = 0; nt < 4; ++nt) {
      int n = n0 + wc * 64 + nt * 16 + c;
      float bv = bias[n];
      int m_base = m0 + wr * 64 + mt * 16 + g * 4;
      if (EPI == 0) {
        int h = n / 192, e = n % 192;
        int bb2 = m_base >> 11, s0 = m_base & 2047;
        if (e < 64) {
#pragma unroll
          for (int r = 0; r < 4; ++r)
            qb[((size_t)(bb2 * H_ + h) * S_ + s0 + r) * HD_ + e] = f2bf((acc[mt][nt][r] + bv) * QSCALE);
        } else if (e < 128) {
#pragma unroll
          for (int r = 0; r < 4; ++r)
            kb[((size_t)(bb2 * H_ + h) * S_ + s0 + r) * HD_ + e - 64] = f2bf(acc[mt][nt][r] + bv);
        } else {
          short4_t vv;
#pragma unroll
          for (int r = 0; r < 4; ++r) vv[r] = f2bf(acc[mt][nt][r] + bv);
          *reinterpret_cast<short4_t*>(
              &vt[((size_t)(bb2 * H_ + h) * HD_ + (e - 128)) * S_ + s0]) = vv;
        }
      } else {
#pragma unroll
        for (int r = 0; r < 4; ++r)
          out[(size_t)(m_base + r) * D_ + n] = acc[mt][nt][r] + bv;
      }
    }
  }
}

// ---------------- causal flash attention, barrier-free, no-max softmax ----------------
struct KF { short8 f[8]; };   // [cc*4 + t]

__device__ __forceinline__ void load_kf(KF& k, const short* __restrict__ kbh,
                                        int k0, int c, int g) {
#pragma unroll
  for (int cc = 0; cc < 2; ++cc)
#pragma unroll
    for (int t = 0; t < 4; ++t)
      k.f[cc * 4 + t] = *reinterpret_cast<const short8*>(
          &kbh[(size_t)(k0 + t * 16 + c) * HD_ + cc * 32 + g * 8]);
}

__global__ __launch_bounds__(256, 2) void attn_kernel(
    const short* __restrict__ qb, const short* __restrict__ kb,
    const short* __restrict__ vt, short* __restrict__ av) {
  // 1024 blocks: one 128-row q-tile each.
  // XCD chunking: xcd = orig&7 owns bh octet (4MB KV = one L2);
  // qt descends within the chunk so every CU holds a long/short mix.
  const int orig = blockIdx.x;
  const int xcd = orig & 7;
  const int local = orig >> 3;            // 0..127
  const int bh = xcd * 8 + (local & 7);   // 0..63
  const int qt = 15 - (local >> 3);       // 15..0
  const int bb = bh >> 4, h = bh & 15;
  const int tid = threadIdx.x;
  const int lane = tid & 63, wv = tid >> 6;
  const int g = lane >> 4, c = lane & 15;
  const int q0 = qt * 128;
  const int r0 = q0 + wv * 32;

  __shared__ short Ps[4][32 * 72];
  short* Pw = Ps[wv];

  const short* qbh = qb + (size_t)bh * S_ * HD_;
  const short* kbh = kb + (size_t)bh * S_ * HD_;
  const short* vth = vt + (size_t)bh * HD_ * S_;

  short8 ones;
#pragma unroll
  for (int j = 0; j < 8; ++j) ones[j] = (short)0x3F80;  // bf16 1.0

  const f32x4 zero4 = {0.f, 0.f, 0.f, 0.f};

  short8 qf[2][2];
#pragma unroll
  for (int mt = 0; mt < 2; ++mt)
#pragma unroll
    for (int cc = 0; cc < 2; ++cc)
      qf[mt][cc] = *reinterpret_cast<const short8*>(
          &qbh[(size_t)(r0 + mt * 16 + c) * HD_ + cc * 32 + g * 8]);

  f32x4 acc_o[2][4];
  f32x4 lacc[2];
#pragma unroll
  for (int mt = 0; mt < 2; ++mt) {
    lacc[mt] = zero4;
#pragma unroll
    for (int nt = 0; nt < 4; ++nt) acc_o[mt][nt] = zero4;
  }

  const int nk = 2 * qt + 2;   // always even

  KF kA, kB;
  load_kf(kA, kbh, 0, c, g);

  auto body = [&](int ktb, KF& kc, KF& kn) {
    const int k0 = ktb * 64;
    // V fragments (global, L2) — issued early, consumed after softmax
    short8 vf[2][4];
#pragma unroll
    for (int cc = 0; cc < 2; ++cc)
#pragma unroll
      for (int nt = 0; nt < 4; ++nt)
        vf[cc][nt] = *reinterpret_cast<const short8*>(
            &vth[(size_t)(nt * 16 + c) * S_ + k0 + cc * 32 + g * 8]);
    // QK^T
    f32x4 sc[2][4];
#pragma unroll
    for (int mt = 0; mt < 2; ++mt)
#pragma unroll
      for (int t = 0; t < 4; ++t) sc[mt][t] = zero4;
#pragma unroll
    for (int cc = 0; cc < 2; ++cc)
#pragma unroll
      for (int mt = 0; mt < 2; ++mt)
#pragma unroll
        for (int t = 0; t < 4; ++t)
          sc[mt][t] = __builtin_amdgcn_mfma_f32_16x16x32_bf16(
              qf[mt][cc], kc.f[cc * 4 + t], sc[mt][t], 0, 0, 0);
    // prefetch next K tile
    int k0n = k0 + 64;
    if (k0n >= S_) k0n = 0;
    load_kf(kn, kbh, k0n, c, g);
    // causal mask — only the last two tiles need it
    if (ktb >= 2 * qt) {
#pragma unroll
      for (int mt = 0; mt < 2; ++mt)
#pragma unroll
        for (int t = 0; t < 4; ++t) {
          const int key = k0 + t * 16 + c;
#pragma unroll
          for (int r = 0; r < 4; ++r) {
            const int qi = r0 + mt * 16 + g * 4 + r;
            if (key > qi) sc[mt][t][r] = -INFINITY;
          }
        }
    }
    // P = exp2(s'), bf16 -> per-wave LDS
#pragma unroll
    for (int mt = 0; mt < 2; ++mt)
#pragma unroll
      for (int t = 0; t < 4; ++t)
#pragma unroll
        for (int r = 0; r < 4; ++r) {
          float pf = __builtin_exp2f(sc[mt][t][r]);
          Pw[(mt * 16 + g * 4 + r) * 72 + t * 16 + c] = f2bf(pf);
        }
    // P fragments back
    short8 pa[2][2];
#pragma unroll
    for (int mt = 0; mt < 2; ++mt)
#pragma unroll
      for (int cc = 0; cc < 2; ++cc)
        pa[mt][cc] = *reinterpret_cast<const short8*>(
            &Pw[(mt * 16 + c) * 72 + cc * 32 + g * 8]);
    // row-sum via ones-MFMA
#pragma unroll
    for (int mt = 0; mt < 2; ++mt) {
      lacc[mt] = __builtin_amdgcn_mfma_f32_16x16x32_bf16(pa[mt][0], ones, lacc[mt], 0, 0, 0);
      lacc[mt] = __builtin_amdgcn_mfma_f32_16x16x32_bf16(pa[mt][1], ones, lacc[mt], 0, 0, 0);
    }
    // PV
#pragma unroll
    for (int cc = 0; cc < 2; ++cc)
#pragma unroll
      for (int mt = 0; mt < 2; ++mt)
#pragma unroll
        for (int nt = 0; nt < 4; ++nt)
          acc_o[mt][nt] = __builtin_amdgcn_mfma_f32_16x16x32_bf16(
              pa[mt][cc], vf[cc][nt], acc_o[mt][nt], 0, 0, 0);
  };

  for (int ktb = 0; ktb < nk; ktb += 2) {
    body(ktb,     kA, kB);
    body(ktb + 1, kB, kA);
  }

  // epilogue: out = acc/l, head-concat [B,S,D]
#pragma unroll
  for (int mt = 0; mt < 2; ++mt) {
    float inv[4];
#pragma unroll
    for (int r = 0; r < 4; ++r) inv[r] = 1.0f / lacc[mt][r];
#pragma unroll
    for (int nt = 0; nt < 4; ++nt)
#pragma unroll
      for (int r = 0; r < 4; ++r) {
        int R = r0 + mt * 16 + g * 4 + r;
        av[(size_t)(bb * S_ + R) * D_ + h * HD_ + nt * 16 + c] =
            f2bf(acc_o[mt][nt][r] * inv[r]);
      }
  }
}

extern "C" void kernel_launch(void* const* d_in, const int* in_sizes, int n_in,
                              void* d_out, int out_size, void* d_ws, size_t ws_size,
                              hipStream_t stream) {
  const float* x    = (const float*)d_in[0];
  const float* Wqkv = (const float*)d_in[1];
  const float* bqkv = (const float*)d_in[2];
  const float* Wo   = (const float*)d_in[3];
  const float* bo   = (const float*)d_in[4];
  float* out = (float*)d_out;

  const size_t NTOK = (size_t)B_ * H_ * S_ * HD_;  // 8,388,608
  short* xb    = (short*)d_ws;                     // 16 MB
  short* wqkvt = xb + (size_t)M_TOK * D_;          // 6 MB
  short* wot   = wqkvt + (size_t)3072 * 1024;      // 2 MB
  short* qb    = wot + (size_t)1024 * 1024;        // 16 MB
  short* kb    = qb + NTOK;                        // 16 MB
  short* vt    = kb + NTOK;                        // 16 MB (transposed V)
  short* av    = xb;                               // alias: xb dead after qkv GEMM

  conv_x_kernel   <<<4096, 256, 0, stream>>>(x, xb);
  conv_wqkv_kernel<<<dim3(16, 32), 256, 0, stream>>>(Wqkv, wqkvt);
  conv_wo_kernel  <<<dim3(32, 8), 256, 0, stream>>>(Wo, wot);
  gemm_kernel<0>  <<<dim3(64, 24), 256, 0, stream>>>(xb, wqkvt, bqkv, qb, kb, vt, nullptr);
  attn_kernel     <<<1024, 256, 0, stream>>>(qb, kb, vt, av);
  gemm_kernel<1>  <<<dim3(64, 8), 256, 0, stream>>>(av, wot, bo, nullptr, nullptr, nullptr, out);
}

// Round 6
// 251.344 us; speedup vs baseline: 1.0093x; 1.0093x over previous
//
#include <hip/hip_runtime.h>
#include <hip/hip_bf16.h>

#define B_ 4
#define S_ 2048
#define D_ 1024
#define H_ 16
#define HD_ 64
#define M_TOK 8192   // B*S
#define QSCALE 0.18033688f   // 0.125 * log2(e)

typedef __attribute__((ext_vector_type(4))) float f32x4;
typedef __attribute__((ext_vector_type(8))) short short8;
typedef __attribute__((ext_vector_type(4))) short short4_t;

__device__ inline short f2bf(float f) {
  unsigned u = __builtin_bit_cast(unsigned, f);
  u += 0x7fff + ((u >> 16) & 1);   // RNE
  return (short)(u >> 16);
}
__device__ inline short f2bf_trunc(float f) {
  return (short)(__builtin_bit_cast(unsigned, f) >> 16);  // RTZ: 1 instr
}

typedef __attribute__((address_space(1))) const unsigned int gas_u32;
typedef __attribute__((address_space(3))) unsigned int las_u32;
__device__ inline void gload_lds16(const void* g, void* l) {
  __builtin_amdgcn_global_load_lds((gas_u32*)g, (las_u32*)l, 16, 0, 0);
}

// ---------------- conversion kernels ----------------
__global__ __launch_bounds__(256) void conv_x_kernel(
    const float* __restrict__ x, short* __restrict__ xb) {
  size_t base = ((size_t)blockIdx.x * 256 + threadIdx.x) * 8;
  f32x4 v0 = *reinterpret_cast<const f32x4*>(&x[base]);
  f32x4 v1 = *reinterpret_cast<const f32x4*>(&x[base + 4]);
  short8 o;
  o[0]=f2bf(v0[0]); o[1]=f2bf(v0[1]); o[2]=f2bf(v0[2]); o[3]=f2bf(v0[3]);
  o[4]=f2bf(v1[0]); o[5]=f2bf(v1[1]); o[6]=f2bf(v1[2]); o[7]=f2bf(v1[3]);
  *reinterpret_cast<short8*>(&xb[base]) = o;
}

__global__ __launch_bounds__(256) void conv_wqkv_kernel(
    const float* __restrict__ Wqkv, short* __restrict__ wqkvt) {
  const int h = blockIdx.x;
  const int k0 = blockIdx.y * 32;
  const int tid = threadIdx.x;
  __shared__ short T[192 * 40];
#pragma unroll
  for (int i = 0; i < 6; ++i) {
    int iv = tid + i * 256;
    int k = iv / 48;
    int e4 = (iv % 48) * 4;
    f32x4 v = *reinterpret_cast<const f32x4*>(&Wqkv[((size_t)h * D_ + k0 + k) * 192 + e4]);
#pragma unroll
    for (int j = 0; j < 4; ++j) T[(e4 + j) * 40 + k] = f2bf(v[j]);
  }
  __syncthreads();
#pragma unroll
  for (int i = 0; i < 6; ++i) {
    int iv = tid + i * 256;
    int e = iv >> 3;
    int g4 = iv & 7;
    short4_t o = *reinterpret_cast<const short4_t*>(&T[e * 40 + g4 * 4]);
    *reinterpret_cast<short4_t*>(&wqkvt[(size_t)(h * 192 + e) * 1024 + k0 + g4 * 4]) = o;
  }
}

__global__ __launch_bounds__(256) void conv_wo_kernel(
    const float* __restrict__ Wo, short* __restrict__ wot) {
  const int k0 = blockIdx.x * 32;
  const int n0 = blockIdx.y * 128;
  const int tid = threadIdx.x;
  __shared__ short T[128 * 40];
#pragma unroll
  for (int i = 0; i < 4; ++i) {
    int iv = tid + i * 256;
    int k = iv >> 5;
    int n4 = (iv & 31) * 4;
    f32x4 v = *reinterpret_cast<const f32x4*>(&Wo[(size_t)(k0 + k) * 1024 + n0 + n4]);
#pragma unroll
    for (int j = 0; j < 4; ++j) T[(n4 + j) * 40 + k] = f2bf(v[j]);
  }
  __syncthreads();
#pragma unroll
  for (int i = 0; i < 4; ++i) {
    int iv = tid + i * 256;
    int e = iv >> 3;
    int g4 = iv & 7;
    short4_t o = *reinterpret_cast<const short4_t*>(&T[e * 40 + g4 * 4]);
    *reinterpret_cast<short4_t*>(&wot[(size_t)(n0 + e) * 1024 + k0 + g4 * 4]) = o;
  }
}

// ---------------- m97-style GEMM: C[M][N] = A[M][K] @ Bt[N][K]^T + bias ----------------
template<int EPI>
__global__ __launch_bounds__(256) void gemm_kernel(
    const short* __restrict__ A, const short* __restrict__ Bt,
    const float* __restrict__ bias,
    short* __restrict__ qb, short* __restrict__ kb, short* __restrict__ vt,
    float* __restrict__ out) {
  const int m0 = blockIdx.x * 128;
  const int n0 = blockIdx.y * 128;
  const int tid = threadIdx.x;
  const int lane = tid & 63, wv = tid >> 6;
  const int wr = wv >> 1, wc = wv & 1;
  const int g = lane >> 4, c = lane & 15;

  __shared__ short As[128 * 32];
  __shared__ short Bs[128 * 32];

  const f32x4 zero4 = {0.f, 0.f, 0.f, 0.f};
  f32x4 acc[4][4];
#pragma unroll
  for (int i = 0; i < 4; ++i)
#pragma unroll
    for (int j = 0; j < 4; ++j) acc[i][j] = zero4;

  const int row_l = tid >> 2;
  const int chunk = tid & 3;
  const short* ga = A  + (size_t)(m0 + row_l) * D_ + chunk * 8;
  const short* gb = Bt + (size_t)(n0 + row_l) * D_ + chunk * 8;
  char* lA = (char*)As + tid * 16;
  char* lB = (char*)Bs + tid * 16;

  for (int k0 = 0; k0 < D_; k0 += 32) {
    gload_lds16(ga + k0,            lA);
    gload_lds16(ga + 64 * D_ + k0,  lA + 4096);
    gload_lds16(gb + k0,            lB);
    gload_lds16(gb + 64 * D_ + k0,  lB + 4096);
    asm volatile("s_waitcnt vmcnt(0)" ::: "memory");
    __syncthreads();
    short8 a[4], b[4];
#pragma unroll
    for (int t = 0; t < 4; ++t) {
      a[t] = *reinterpret_cast<const short8*>(&As[(wr * 64 + t * 16 + c) * 32 + g * 8]);
      b[t] = *reinterpret_cast<const short8*>(&Bs[(wc * 64 + t * 16 + c) * 32 + g * 8]);
    }
#pragma unroll
    for (int mt = 0; mt < 4; ++mt)
#pragma unroll
      for (int nt = 0; nt < 4; ++nt)
        acc[mt][nt] = __builtin_amdgcn_mfma_f32_16x16x32_bf16(a[mt], b[nt], acc[mt][nt], 0, 0, 0);
    __syncthreads();
  }

#pragma unroll
  for (int mt = 0; mt < 4; ++mt) {
#pragma unroll
    for (int nt = 0; nt < 4; ++nt) {
      int n = n0 + wc * 64 + nt * 16 + c;
      float bv = bias[n];
      int m_base = m0 + wr * 64 + mt * 16 + g * 4;
      if (EPI == 0) {
        int h = n / 192, e = n % 192;
        int bb2 = m_base >> 11, s0 = m_base & 2047;
        if (e < 64) {
#pragma unroll
          for (int r = 0; r < 4; ++r)
            qb[((size_t)(bb2 * H_ + h) * S_ + s0 + r) * HD_ + e] = f2bf((acc[mt][nt][r] + bv) * QSCALE);
        } else if (e < 128) {
#pragma unroll
          for (int r = 0; r < 4; ++r)
            kb[((size_t)(bb2 * H_ + h) * S_ + s0 + r) * HD_ + e - 64] = f2bf(acc[mt][nt][r] + bv);
        } else {
          short4_t vv;
#pragma unroll
          for (int r = 0; r < 4; ++r) vv[r] = f2bf(acc[mt][nt][r] + bv);
          *reinterpret_cast<short4_t*>(
              &vt[((size_t)(bb2 * H_ + h) * HD_ + (e - 128)) * S_ + s0]) = vv;
        }
      } else {
#pragma unroll
        for (int r = 0; r < 4; ++r)
          out[(size_t)(m_base + r) * D_ + n] = acc[mt][nt][r] + bv;
      }
    }
  }
}

// ---------------- causal flash attention: 32-key tiles, barrier-free ----------------
struct KF32 { short8 f[4]; };   // [cc*2 + t]

__device__ __forceinline__ void load_kf32(KF32& k, const short* __restrict__ kbh,
                                          int k0, int c, int g) {
#pragma unroll
  for (int cc = 0; cc < 2; ++cc)
#pragma unroll
    for (int t = 0; t < 2; ++t)
      k.f[cc * 2 + t] = *reinterpret_cast<const short8*>(
          &kbh[(size_t)(k0 + t * 16 + c) * HD_ + cc * 32 + g * 8]);
}

__global__ __launch_bounds__(256, 3) void attn_kernel(
    const short* __restrict__ qb, const short* __restrict__ kb,
    const short* __restrict__ vt, short* __restrict__ av) {
  // 1024 blocks; xcd = orig&7 owns one bh octet (4MB KV = one L2);
  // qt descends with local index so each CU gets a long/short mix.
  const int orig = blockIdx.x;
  const int xcd = orig & 7;
  const int local = orig >> 3;            // 0..127
  const int bh = xcd * 8 + (local & 7);   // 0..63
  const int qt = 15 - (local >> 3);       // 15..0
  const int bb = bh >> 4, h = bh & 15;
  const int tid = threadIdx.x;
  const int lane = tid & 63, wv = tid >> 6;
  const int g = lane >> 4, c = lane & 15;
  const int q0 = qt * 128;
  const int r0 = q0 + wv * 32;

  __shared__ short Ps[4][32 * 40];        // per-wave P [32 rows][32 keys], stride 40
  short* Pw = Ps[wv];

  const short* qbh = qb + (size_t)bh * S_ * HD_;
  const short* kbh = kb + (size_t)bh * S_ * HD_;
  const short* vth = vt + (size_t)bh * HD_ * S_;

  short8 ones;
#pragma unroll
  for (int j = 0; j < 8; ++j) ones[j] = (short)0x3F80;  // bf16 1.0

  const f32x4 zero4 = {0.f, 0.f, 0.f, 0.f};

  short8 qf[2][2];
#pragma unroll
  for (int mt = 0; mt < 2; ++mt)
#pragma unroll
    for (int cc = 0; cc < 2; ++cc)
      qf[mt][cc] = *reinterpret_cast<const short8*>(
          &qbh[(size_t)(r0 + mt * 16 + c) * HD_ + cc * 32 + g * 8]);

  f32x4 acc_o[2][4];
  f32x4 lacc[2];
#pragma unroll
  for (int mt = 0; mt < 2; ++mt) {
    lacc[mt] = zero4;
#pragma unroll
    for (int nt = 0; nt < 4; ++nt) acc_o[mt][nt] = zero4;
  }

  const int diag = 4 * qt + wv;   // wave's diagonal 32-key tile
  const int nk = diag + 1;        // per-wave causal bound

  KF32 kA, kB;
  load_kf32(kA, kbh, 0, c, g);

  auto body = [&](int ktb, KF32& kc, KF32& kn) {
    const int k0 = ktb * 32;
    // V fragments (global, L2) — issued first, consumed after softmax
    short8 vf[4];
#pragma unroll
    for (int nt = 0; nt < 4; ++nt)
      vf[nt] = *reinterpret_cast<const short8*>(
          &vth[(size_t)(nt * 16 + c) * S_ + k0 + g * 8]);
    // QK^T
    f32x4 sc[2][2];
#pragma unroll
    for (int mt = 0; mt < 2; ++mt)
#pragma unroll
      for (int t = 0; t < 2; ++t) sc[mt][t] = zero4;
#pragma unroll
    for (int cc = 0; cc < 2; ++cc)
#pragma unroll
      for (int mt = 0; mt < 2; ++mt)
#pragma unroll
        for (int t = 0; t < 2; ++t)
          sc[mt][t] = __builtin_amdgcn_mfma_f32_16x16x32_bf16(
              qf[mt][cc], kc.f[cc * 2 + t], sc[mt][t], 0, 0, 0);
    // prefetch next K tile (one body ahead)
    int k0n = k0 + 32;
    if (k0n >= S_) k0n = 0;
    load_kf32(kn, kbh, k0n, c, g);
    // causal mask — only the wave's diagonal tile
    if (ktb == diag) {
#pragma unroll
      for (int mt = 0; mt < 2; ++mt)
#pragma unroll
        for (int t = 0; t < 2; ++t) {
          const int key = k0 + t * 16 + c;
#pragma unroll
          for (int r = 0; r < 4; ++r) {
            const int qi = r0 + mt * 16 + g * 4 + r;
            if (key > qi) sc[mt][t][r] = -INFINITY;
          }
        }
    }
    // P = exp2(s'), truncate to bf16 -> per-wave LDS
#pragma unroll
    for (int mt = 0; mt < 2; ++mt)
#pragma unroll
      for (int t = 0; t < 2; ++t)
#pragma unroll
        for (int r = 0; r < 4; ++r) {
          float pf = __builtin_exp2f(sc[mt][t][r]);
          Pw[(mt * 16 + g * 4 + r) * 40 + t * 16 + c] = f2bf_trunc(pf);
        }
    // P fragments back (row = mt*16+c, k-slot g*8+j)
    short8 pa[2];
#pragma unroll
    for (int mt = 0; mt < 2; ++mt)
      pa[mt] = *reinterpret_cast<const short8*>(&Pw[(mt * 16 + c) * 40 + g * 8]);
    // row-sum via ones-MFMA
#pragma unroll
    for (int mt = 0; mt < 2; ++mt)
      lacc[mt] = __builtin_amdgcn_mfma_f32_16x16x32_bf16(pa[mt], ones, lacc[mt], 0, 0, 0);
    // PV (one K=32 MFMA per output tile)
#pragma unroll
    for (int mt = 0; mt < 2; ++mt)
#pragma unroll
      for (int nt = 0; nt < 4; ++nt)
        acc_o[mt][nt] = __builtin_amdgcn_mfma_f32_16x16x32_bf16(
            pa[mt], vf[nt], acc_o[mt][nt], 0, 0, 0);
  };

  int ktb = 0;
  for (; ktb + 1 < nk; ktb += 2) {
    body(ktb,     kA, kB);
    body(ktb + 1, kB, kA);
  }
  if (ktb < nk) body(ktb, kA, kB);

  // epilogue: out = acc/l, head-concat [B,S,D]
#pragma unroll
  for (int mt = 0; mt < 2; ++mt) {
    float inv[4];
#pragma unroll
    for (int r = 0; r < 4; ++r) inv[r] = 1.0f / lacc[mt][r];
#pragma unroll
    for (int nt = 0; nt < 4; ++nt)
#pragma unroll
      for (int r = 0; r < 4; ++r) {
        int R = r0 + mt * 16 + g * 4 + r;
        av[(size_t)(bb * S_ + R) * D_ + h * HD_ + nt * 16 + c] =
            f2bf(acc_o[mt][nt][r] * inv[r]);
      }
  }
}

extern "C" void kernel_launch(void* const* d_in, const int* in_sizes, int n_in,
                              void* d_out, int out_size, void* d_ws, size_t ws_size,
                              hipStream_t stream) {
  const float* x    = (const float*)d_in[0];
  const float* Wqkv = (const float*)d_in[1];
  const float* bqkv = (const float*)d_in[2];
  const float* Wo   = (const float*)d_in[3];
  const float* bo   = (const float*)d_in[4];
  float* out = (float*)d_out;

  const size_t NTOK = (size_t)B_ * H_ * S_ * HD_;  // 8,388,608
  short* xb    = (short*)d_ws;                     // 16 MB
  short* wqkvt = xb + (size_t)M_TOK * D_;          // 6 MB
  short* wot   = wqkvt + (size_t)3072 * 1024;      // 2 MB
  short* qb    = wot + (size_t)1024 * 1024;        // 16 MB
  short* kb    = qb + NTOK;                        // 16 MB
  short* vt    = kb + NTOK;                        // 16 MB (transposed V)
  short* av    = xb;                               // alias: xb dead after qkv GEMM

  conv_x_kernel   <<<4096, 256, 0, stream>>>(x, xb);
  conv_wqkv_kernel<<<dim3(16, 32), 256, 0, stream>>>(Wqkv, wqkvt);
  conv_wo_kernel  <<<dim3(32, 8), 256, 0, stream>>>(Wo, wot);
  gemm_kernel<0>  <<<dim3(64, 24), 256, 0, stream>>>(xb, wqkvt, bqkv, qb, kb, vt, nullptr);
  attn_kernel     <<<1024, 256, 0, stream>>>(qb, kb, vt, av);
  gemm_kernel<1>  <<<dim3(64, 8), 256, 0, stream>>>(av, wot, bo, nullptr, nullptr, nullptr, out);
}

// Round 7
// 183.306 us; speedup vs baseline: 1.3839x; 1.3712x over previous
//
#include <hip/hip_runtime.h>
#include <hip/hip_bf16.h>

#define B_ 4
#define S_ 2048
#define D_ 1024
#define H_ 16
#define HD_ 64
#define M_TOK 8192   // B*S
#define QSCALE 0.18033688f   // 0.125 * log2(e)

typedef __attribute__((ext_vector_type(4))) float f32x4;
typedef __attribute__((ext_vector_type(8))) short short8;
typedef __attribute__((ext_vector_type(4))) short short4_t;

__device__ inline short f2bf(float f) {
  unsigned u = __builtin_bit_cast(unsigned, f);
  u += 0x7fff + ((u >> 16) & 1);   // RNE
  return (short)(u >> 16);
}
__device__ inline short f2bf_trunc(float f) {
  return (short)(__builtin_bit_cast(unsigned, f) >> 16);  // RTZ: 1 instr
}

typedef __attribute__((address_space(1))) const unsigned int gas_u32;
typedef __attribute__((address_space(3))) unsigned int las_u32;
__device__ inline void gload_lds16(const void* g, void* l) {
  __builtin_amdgcn_global_load_lds((gas_u32*)g, (las_u32*)l, 16, 0, 0);
}

// Fragment-packed layouts (per (b,h) plane):
//   Q/K: idx(s,e)  = (s>>4)*1024 + (e>>3)*128 + (s&15)*8 + (e&7)     [S*HD shorts]
//   V:   idx(hd,s) = ((hd>>4)*64 + (s>>5))*512 + ((s>>3)&3)*128 + (hd&15)*8 + (s&7)
// Wave fragment load = base + lane*8 shorts (contiguous 1KB).

// ---------------- conversion kernels ----------------
__global__ __launch_bounds__(256) void conv_x_kernel(
    const float* __restrict__ x, short* __restrict__ xb) {
  size_t base = ((size_t)blockIdx.x * 256 + threadIdx.x) * 8;
  f32x4 v0 = *reinterpret_cast<const f32x4*>(&x[base]);
  f32x4 v1 = *reinterpret_cast<const f32x4*>(&x[base + 4]);
  short8 o;
  o[0]=f2bf(v0[0]); o[1]=f2bf(v0[1]); o[2]=f2bf(v0[2]); o[3]=f2bf(v0[3]);
  o[4]=f2bf(v1[0]); o[5]=f2bf(v1[1]); o[6]=f2bf(v1[2]); o[7]=f2bf(v1[3]);
  *reinterpret_cast<short8*>(&xb[base]) = o;
}

__global__ __launch_bounds__(256) void conv_wqkv_kernel(
    const float* __restrict__ Wqkv, short* __restrict__ wqkvt) {
  const int h = blockIdx.x;
  const int k0 = blockIdx.y * 32;
  const int tid = threadIdx.x;
  __shared__ short T[192 * 40];
#pragma unroll
  for (int i = 0; i < 6; ++i) {
    int iv = tid + i * 256;
    int k = iv / 48;
    int e4 = (iv % 48) * 4;
    f32x4 v = *reinterpret_cast<const f32x4*>(&Wqkv[((size_t)h * D_ + k0 + k) * 192 + e4]);
#pragma unroll
    for (int j = 0; j < 4; ++j) T[(e4 + j) * 40 + k] = f2bf(v[j]);
  }
  __syncthreads();
#pragma unroll
  for (int i = 0; i < 6; ++i) {
    int iv = tid + i * 256;
    int e = iv >> 3;
    int g4 = iv & 7;
    short4_t o = *reinterpret_cast<const short4_t*>(&T[e * 40 + g4 * 4]);
    *reinterpret_cast<short4_t*>(&wqkvt[(size_t)(h * 192 + e) * 1024 + k0 + g4 * 4]) = o;
  }
}

__global__ __launch_bounds__(256) void conv_wo_kernel(
    const float* __restrict__ Wo, short* __restrict__ wot) {
  const int k0 = blockIdx.x * 32;
  const int n0 = blockIdx.y * 128;
  const int tid = threadIdx.x;
  __shared__ short T[128 * 40];
#pragma unroll
  for (int i = 0; i < 4; ++i) {
    int iv = tid + i * 256;
    int k = iv >> 5;
    int n4 = (iv & 31) * 4;
    f32x4 v = *reinterpret_cast<const f32x4*>(&Wo[(size_t)(k0 + k) * 1024 + n0 + n4]);
#pragma unroll
    for (int j = 0; j < 4; ++j) T[(n4 + j) * 40 + k] = f2bf(v[j]);
  }
  __syncthreads();
#pragma unroll
  for (int i = 0; i < 4; ++i) {
    int iv = tid + i * 256;
    int e = iv >> 3;
    int g4 = iv & 7;
    short4_t o = *reinterpret_cast<const short4_t*>(&T[e * 40 + g4 * 4]);
    *reinterpret_cast<short4_t*>(&wot[(size_t)(n0 + e) * 1024 + k0 + g4 * 4]) = o;
  }
}

// ---------------- m97-style GEMM: C[M][N] = A[M][K] @ Bt[N][K]^T + bias ----------------
template<int EPI>
__global__ __launch_bounds__(256) void gemm_kernel(
    const short* __restrict__ A, const short* __restrict__ Bt,
    const float* __restrict__ bias,
    short* __restrict__ qb, short* __restrict__ kb, short* __restrict__ vt,
    float* __restrict__ out) {
  const int m0 = blockIdx.x * 128;
  const int n0 = blockIdx.y * 128;
  const int tid = threadIdx.x;
  const int lane = tid & 63, wv = tid >> 6;
  const int wr = wv >> 1, wc = wv & 1;
  const int g = lane >> 4, c = lane & 15;

  __shared__ short As[128 * 32];
  __shared__ short Bs[128 * 32];

  const f32x4 zero4 = {0.f, 0.f, 0.f, 0.f};
  f32x4 acc[4][4];
#pragma unroll
  for (int i = 0; i < 4; ++i)
#pragma unroll
    for (int j = 0; j < 4; ++j) acc[i][j] = zero4;

  const int row_l = tid >> 2;
  const int chunk = tid & 3;
  const short* ga = A  + (size_t)(m0 + row_l) * D_ + chunk * 8;
  const short* gb = Bt + (size_t)(n0 + row_l) * D_ + chunk * 8;
  char* lA = (char*)As + tid * 16;
  char* lB = (char*)Bs + tid * 16;

  for (int k0 = 0; k0 < D_; k0 += 32) {
    gload_lds16(ga + k0,            lA);
    gload_lds16(ga + 64 * D_ + k0,  lA + 4096);
    gload_lds16(gb + k0,            lB);
    gload_lds16(gb + 64 * D_ + k0,  lB + 4096);
    asm volatile("s_waitcnt vmcnt(0)" ::: "memory");
    __syncthreads();
    short8 a[4], b[4];
#pragma unroll
    for (int t = 0; t < 4; ++t) {
      a[t] = *reinterpret_cast<const short8*>(&As[(wr * 64 + t * 16 + c) * 32 + g * 8]);
      b[t] = *reinterpret_cast<const short8*>(&Bs[(wc * 64 + t * 16 + c) * 32 + g * 8]);
    }
#pragma unroll
    for (int mt = 0; mt < 4; ++mt)
#pragma unroll
      for (int nt = 0; nt < 4; ++nt)
        acc[mt][nt] = __builtin_amdgcn_mfma_f32_16x16x32_bf16(a[mt], b[nt], acc[mt][nt], 0, 0, 0);
    __syncthreads();
  }

#pragma unroll
  for (int mt = 0; mt < 4; ++mt) {
#pragma unroll
    for (int nt = 0; nt < 4; ++nt) {
      int n = n0 + wc * 64 + nt * 16 + c;
      float bv = bias[n];
      int m_base = m0 + wr * 64 + mt * 16 + g * 4;
      if (EPI == 0) {
        int h = n / 192, e = n % 192;
        int bb2 = m_base >> 11, s0 = m_base & 2047;
        size_t plane = (size_t)(bb2 * H_ + h) * (S_ * HD_);
        if (e < 64) {
          size_t bp = plane + (size_t)(s0 >> 4) * 1024 + (e >> 3) * 128 + (s0 & 15) * 8 + (e & 7);
#pragma unroll
          for (int r = 0; r < 4; ++r)
            qb[bp + r * 8] = f2bf((acc[mt][nt][r] + bv) * QSCALE);
        } else if (e < 128) {
          int ek = e - 64;
          size_t bp = plane + (size_t)(s0 >> 4) * 1024 + (ek >> 3) * 128 + (s0 & 15) * 8 + (ek & 7);
#pragma unroll
          for (int r = 0; r < 4; ++r)
            kb[bp + r * 8] = f2bf(acc[mt][nt][r] + bv);
        } else {
          int hd = e - 128;
          size_t bp = plane + (size_t)((hd >> 4) * 64 + (s0 >> 5)) * 512 +
                      ((s0 >> 3) & 3) * 128 + (hd & 15) * 8 + (s0 & 7);
          short4_t vv;
#pragma unroll
          for (int r = 0; r < 4; ++r) vv[r] = f2bf(acc[mt][nt][r] + bv);
          *reinterpret_cast<short4_t*>(&vt[bp]) = vv;
        }
      } else {
#pragma unroll
        for (int r = 0; r < 4; ++r)
          out[(size_t)(m_base + r) * D_ + n] = acc[mt][nt][r] + bv;
      }
    }
  }
}

// ---------------- causal flash attention: 32-key tiles, packed fragments ----------------
struct KF32 { short8 f[4]; };   // [cc*2 + t]

__device__ __forceinline__ void load_kf32(KF32& k, const short* __restrict__ kbh,
                                          int ktb, int lane) {
#pragma unroll
  for (int cc = 0; cc < 2; ++cc)
#pragma unroll
    for (int t = 0; t < 2; ++t)
      k.f[cc * 2 + t] = *reinterpret_cast<const short8*>(
          &kbh[(size_t)(ktb * 2 + t) * 1024 + cc * 512 + lane * 8]);
}

__global__ __launch_bounds__(256, 3) void attn_kernel(
    const short* __restrict__ qb, const short* __restrict__ kb,
    const short* __restrict__ vt, short* __restrict__ av) {
  const int orig = blockIdx.x;
  const int xcd = orig & 7;
  const int local = orig >> 3;            // 0..127
  const int bh = xcd * 8 + (local & 7);   // 0..63
  const int qt = 15 - (local >> 3);       // 15..0
  const int bb = bh >> 4, h = bh & 15;
  const int tid = threadIdx.x;
  const int lane = tid & 63, wv = tid >> 6;
  const int g = lane >> 4, c = lane & 15;
  const int q0 = qt * 128;
  const int r0 = q0 + wv * 32;

  __shared__ short Ps[4][32 * 40];        // per-wave P [32 rows][32 keys], stride 40
  short* Pw = Ps[wv];

  const short* qbh = qb + (size_t)bh * S_ * HD_;
  const short* kbh = kb + (size_t)bh * S_ * HD_;
  const short* vth = vt + (size_t)bh * HD_ * S_;

  short8 ones;
#pragma unroll
  for (int j = 0; j < 8; ++j) ones[j] = (short)0x3F80;  // bf16 1.0

  const f32x4 zero4 = {0.f, 0.f, 0.f, 0.f};

  short8 qf[2][2];
#pragma unroll
  for (int mt = 0; mt < 2; ++mt)
#pragma unroll
    for (int cc = 0; cc < 2; ++cc)
      qf[mt][cc] = *reinterpret_cast<const short8*>(
          &qbh[(size_t)(r0 / 16 + mt) * 1024 + cc * 512 + lane * 8]);

  f32x4 acc_o[2][4];
  f32x4 lacc[2];
#pragma unroll
  for (int mt = 0; mt < 2; ++mt) {
    lacc[mt] = zero4;
#pragma unroll
    for (int nt = 0; nt < 4; ++nt) acc_o[mt][nt] = zero4;
  }

  const int diag = 4 * qt + wv;   // wave's diagonal 32-key tile
  const int nk = diag + 1;

  KF32 kA, kB;
  load_kf32(kA, kbh, 0, lane);

  auto body = [&](int ktb, KF32& kc, KF32& kn) {
    const int k0 = ktb * 32;
    // V fragments: packed, contiguous 1KB per load
    short8 vf[4];
#pragma unroll
    for (int nt = 0; nt < 4; ++nt)
      vf[nt] = *reinterpret_cast<const short8*>(
          &vth[(size_t)(nt * 64 + ktb) * 512 + lane * 8]);
    // QK^T
    f32x4 sc[2][2];
#pragma unroll
    for (int mt = 0; mt < 2; ++mt)
#pragma unroll
      for (int t = 0; t < 2; ++t) sc[mt][t] = zero4;
#pragma unroll
    for (int cc = 0; cc < 2; ++cc)
#pragma unroll
      for (int mt = 0; mt < 2; ++mt)
#pragma unroll
        for (int t = 0; t < 2; ++t)
          sc[mt][t] = __builtin_amdgcn_mfma_f32_16x16x32_bf16(
              qf[mt][cc], kc.f[cc * 2 + t], sc[mt][t], 0, 0, 0);
    // prefetch next K tile
    int ktbn = ktb + 1;
    if (ktbn >= S_ / 32) ktbn = 0;
    load_kf32(kn, kbh, ktbn, lane);
    // causal mask — only the wave's diagonal tile
    if (ktb == diag) {
#pragma unroll
      for (int mt = 0; mt < 2; ++mt)
#pragma unroll
        for (int t = 0; t < 2; ++t) {
          const int key = k0 + t * 16 + c;
#pragma unroll
          for (int r = 0; r < 4; ++r) {
            const int qi = r0 + mt * 16 + g * 4 + r;
            if (key > qi) sc[mt][t][r] = -INFINITY;
          }
        }
    }
    // P = exp2(s'), truncate to bf16 -> per-wave LDS
#pragma unroll
    for (int mt = 0; mt < 2; ++mt)
#pragma unroll
      for (int t = 0; t < 2; ++t)
#pragma unroll
        for (int r = 0; r < 4; ++r) {
          float pf = __builtin_exp2f(sc[mt][t][r]);
          Pw[(mt * 16 + g * 4 + r) * 40 + t * 16 + c] = f2bf_trunc(pf);
        }
    // P fragments back
    short8 pa[2];
#pragma unroll
    for (int mt = 0; mt < 2; ++mt)
      pa[mt] = *reinterpret_cast<const short8*>(&Pw[(mt * 16 + c) * 40 + g * 8]);
    // row-sum via ones-MFMA
#pragma unroll
    for (int mt = 0; mt < 2; ++mt)
      lacc[mt] = __builtin_amdgcn_mfma_f32_16x16x32_bf16(pa[mt], ones, lacc[mt], 0, 0, 0);
    // PV
#pragma unroll
    for (int mt = 0; mt < 2; ++mt)
#pragma unroll
      for (int nt = 0; nt < 4; ++nt)
        acc_o[mt][nt] = __builtin_amdgcn_mfma_f32_16x16x32_bf16(
            pa[mt], vf[nt], acc_o[mt][nt], 0, 0, 0);
  };

  int ktb = 0;
  for (; ktb + 1 < nk; ktb += 2) {
    body(ktb,     kA, kB);
    body(ktb + 1, kB, kA);
  }
  if (ktb < nk) body(ktb, kA, kB);

  // epilogue: out = acc/l, head-concat [B,S,D]
#pragma unroll
  for (int mt = 0; mt < 2; ++mt) {
    float inv[4];
#pragma unroll
    for (int r = 0; r < 4; ++r) inv[r] = 1.0f / lacc[mt][r];
#pragma unroll
    for (int nt = 0; nt < 4; ++nt)
#pragma unroll
      for (int r = 0; r < 4; ++r) {
        int R = r0 + mt * 16 + g * 4 + r;
        av[(size_t)(bb * S_ + R) * D_ + h * HD_ + nt * 16 + c] =
            f2bf(acc_o[mt][nt][r] * inv[r]);
      }
  }
}

extern "C" void kernel_launch(void* const* d_in, const int* in_sizes, int n_in,
                              void* d_out, int out_size, void* d_ws, size_t ws_size,
                              hipStream_t stream) {
  const float* x    = (const float*)d_in[0];
  const float* Wqkv = (const float*)d_in[1];
  const float* bqkv = (const float*)d_in[2];
  const float* Wo   = (const float*)d_in[3];
  const float* bo   = (const float*)d_in[4];
  float* out = (float*)d_out;

  const size_t NTOK = (size_t)B_ * H_ * S_ * HD_;  // 8,388,608
  short* xb    = (short*)d_ws;                     // 16 MB
  short* wqkvt = xb + (size_t)M_TOK * D_;          // 6 MB
  short* wot   = wqkvt + (size_t)3072 * 1024;      // 2 MB
  short* qb    = wot + (size_t)1024 * 1024;        // 16 MB
  short* kb    = qb + NTOK;                        // 16 MB
  short* vt    = kb + NTOK;                        // 16 MB (fragment-packed V)
  short* av    = xb;                               // alias: xb dead after qkv GEMM

  conv_x_kernel   <<<4096, 256, 0, stream>>>(x, xb);
  conv_wqkv_kernel<<<dim3(16, 32), 256, 0, stream>>>(Wqkv, wqkvt);
  conv_wo_kernel  <<<dim3(32, 8), 256, 0, stream>>>(Wo, wot);
  gemm_kernel<0>  <<<dim3(64, 24), 256, 0, stream>>>(xb, wqkvt, bqkv, qb, kb, vt, nullptr);
  attn_kernel     <<<1024, 256, 0, stream>>>(qb, kb, vt, av);
  gemm_kernel<1>  <<<dim3(64, 8), 256, 0, stream>>>(av, wot, bo, nullptr, nullptr, nullptr, out);
}